// Round 19
// baseline (237.724 us; speedup 1.0000x reference)
//
#include <hip/hip_runtime.h>
#include <hip/hip_bf16.h>

#define NN 10000
#define EE 50000
#define TT 80000
#define DD 16
#define HH 128
#define CC 64

typedef __hip_bfloat16 bf16;
typedef __attribute__((ext_vector_type(8))) short bf16x8;
typedef __attribute__((ext_vector_type(4))) short bf16x4;
typedef __attribute__((ext_vector_type(4))) float f32x4;

__device__ __forceinline__ float silu_f(float x) {
  return x * __builtin_amdgcn_rcpf(1.f + __expf(-x));
}
__device__ __forceinline__ float sigm_f(float x) {
  return __builtin_amdgcn_rcpf(1.f + __expf(-x));
}

__device__ __forceinline__ short f2bs(float x) {
  __hip_bfloat16 h = __float2bfloat16(x);
  short s;
  __builtin_memcpy(&s, &h, 2);
  return s;
}

__device__ __forceinline__ float rnorm_f(float ss) {
  return __builtin_amdgcn_rcpf(fmaxf(__builtin_amdgcn_sqrtf(ss), 1e-12f));
}

__device__ __forceinline__ void bf2x(unsigned u, float& lo, float& hi) {
  lo = __uint_as_float(u << 16);
  hi = __uint_as_float(u & 0xffff0000u);
}

#define ZERO_U4 960000  // (EE*CC*4 + NN*CC*4) / 16 bytes

// K2 split by OUTPUT half: each kernel recomputes GEMM1 (cheap) but holds
// only HALF of the W_c2 fragments -> ~115 peak regs -> 3 waves/SIMD.
// HALF=0 -> cji2 (no norm) + node projection + zeroing; HALF=1 -> ckjn (norm).
#define K2_BLOCKS 2048
#define K2_TILES 50000  // (EE*DD)/16
template <int HALF>
__global__ __launch_bounds__(256, 3) void k_coeffs_h(
    const float* __restrict__ cji, const float* __restrict__ W_c1,
    const float* __restrict__ W_c2, bf16* __restrict__ outbuf,
    const float* __restrict__ x, const float* __restrict__ W_nb,
    const float* __restrict__ b_nb, float* __restrict__ sxq,
    float* __restrict__ sigxk, uint4* __restrict__ zero_p) {
  __shared__ __align__(16) float xs[16][HH];
  const int tid = threadIdx.x;
  const int bid = blockIdx.x;
  const int w = tid >> 6, l = tid & 63;
  const int lr = l & 15, lg = l >> 4;

  if (HALF == 0) {
    for (int i = bid * 256 + tid; i < ZERO_U4; i += K2_BLOCKS * 256)
      zero_p[i] = (uint4){0u, 0u, 0u, 0u};

    if (bid < NN / 16) {
      const int g = tid >> 7, c = tid & 127;
      const int nb = bid * 16 + g * 8;
#pragma unroll
      for (int i = 0; i < 8; ++i)
        xs[g * 8 + i][c] = x[(size_t)(nb + i) * HH + c];
      __syncthreads();
      float acc[8];
      const float bb = b_nb[c];
#pragma unroll
      for (int i = 0; i < 8; ++i) acc[i] = bb;
      for (int k = 0; k < HH; k += 4) {
        const float w0 = W_nb[(k + 0) * HH + c];
        const float w1 = W_nb[(k + 1) * HH + c];
        const float w2 = W_nb[(k + 2) * HH + c];
        const float w3 = W_nb[(k + 3) * HH + c];
#pragma unroll
        for (int i = 0; i < 8; ++i) {
          const float4 xv = *(const float4*)(&xs[g * 8 + i][k]);
          acc[i] = fmaf(xv.x, w0, acc[i]);
          acc[i] = fmaf(xv.y, w1, acc[i]);
          acc[i] = fmaf(xv.z, w2, acc[i]);
          acc[i] = fmaf(xv.w, w3, acc[i]);
        }
      }
      if (c < CC) {
#pragma unroll
        for (int i = 0; i < 8; ++i)
          sxq[(size_t)(nb + i) * CC + c] = silu_f(acc[i]);
      } else {
#pragma unroll
        for (int i = 0; i < 8; ++i)
          sigxk[(size_t)(nb + i) * CC + (c - CC)] = sigm_f(acc[i]);
      }
    }
  }

  // weights: full W_c1^T, HALF of W_c2 (32+32 VGPR)
  bf16x4 bw1[4][4];
  bf16x4 bw2[4][4];
#pragma unroll
  for (int rt = 0; rt < 4; ++rt)
#pragma unroll
    for (int kt = 0; kt < 4; ++kt) {
      bf16x4 t;
#pragma unroll
      for (int b = 0; b < 4; ++b)
        t[b] = f2bs(W_c1[(kt * 16 + lg * 4 + b) * 64 + rt * 16 + lr]);
      bw1[rt][kt] = t;
    }
#pragma unroll
  for (int kt = 0; kt < 4; ++kt)
#pragma unroll
    for (int ct = 0; ct < 4; ++ct) {
      bf16x4 t;
#pragma unroll
      for (int b = 0; b < 4; ++b)
        t[b] = f2bs(W_c2[(kt * 16 + lg * 4 + b) * 128 + (HALF * 4 + ct) * 16 + lr]);
      bw2[kt][ct] = t;
    }

  const int nwave = K2_BLOCKS * 4;
  int tile = bid * 4 + w;
  if (tile >= K2_TILES) return;

  float4 r[4];
#pragma unroll
  for (int kt = 0; kt < 4; ++kt)
    r[kt] = *(const float4*)(cji + (size_t)tile * 1024 + lr * 64 + kt * 16 + lg * 4);

  for (; tile < K2_TILES; tile += nwave) {
    bf16x4 sB[4];
#pragma unroll
    for (int kt = 0; kt < 4; ++kt) {
      bf16x4 t;
      t[0] = f2bs(silu_f(r[kt].x));
      t[1] = f2bs(silu_f(r[kt].y));
      t[2] = f2bs(silu_f(r[kt].z));
      t[3] = f2bs(silu_f(r[kt].w));
      sB[kt] = t;
    }

    const int next = tile + nwave;
    if (next < K2_TILES) {
#pragma unroll
      for (int kt = 0; kt < 4; ++kt)
        r[kt] = *(const float4*)(cji + (size_t)next * 1024 + lr * 64 + kt * 16 + lg * 4);
    }

    // GEMM1 swapped: acc1[rt][j] = t1[lr][16rt+4lg+j]
    f32x4 acc1[4];
#pragma unroll
    for (int rt = 0; rt < 4; ++rt) acc1[rt] = (f32x4){0.f, 0.f, 0.f, 0.f};
#pragma unroll
    for (int rt = 0; rt < 4; ++rt)
#pragma unroll
      for (int kt = 0; kt < 4; ++kt)
        acc1[rt] = __builtin_amdgcn_mfma_f32_16x16x16bf16_1k(bw1[rt][kt], sB[kt], acc1[rt], 0, 0, 0);

    // silu -> GEMM2 A-frags directly (rt == kt, j == b)
    bf16x4 tf[4];
#pragma unroll
    for (int kt = 0; kt < 4; ++kt) {
      bf16x4 t;
#pragma unroll
      for (int b = 0; b < 4; ++b) t[b] = f2bs(silu_f(acc1[kt][b]));
      tf[kt] = t;
    }

    // GEMM2: this half's 4 column tiles
    f32x4 acc2[4];
#pragma unroll
    for (int ct = 0; ct < 4; ++ct) acc2[ct] = (f32x4){0.f, 0.f, 0.f, 0.f};
#pragma unroll
    for (int ct = 0; ct < 4; ++ct)
#pragma unroll
      for (int kt = 0; kt < 4; ++kt)
        acc2[ct] = __builtin_amdgcn_mfma_f32_16x16x16bf16_1k(tf[kt], bw2[kt][ct], acc2[ct], 0, 0, 0);

    union { short h[16]; uint4 u[2]; } p;
    if (HALF == 0) {
#pragma unroll
      for (int ct = 0; ct < 4; ++ct)
#pragma unroll
        for (int j = 0; j < 4; ++j) p.h[ct * 4 + j] = f2bs(acc2[ct][j]);
    } else {
      float rn[4];
#pragma unroll
      for (int j = 0; j < 4; ++j) {
        float ss = acc2[0][j] * acc2[0][j];
        ss = fmaf(acc2[1][j], acc2[1][j], ss);
        ss = fmaf(acc2[2][j], acc2[2][j], ss);
        ss = fmaf(acc2[3][j], acc2[3][j], ss);
#pragma unroll
        for (int m = 1; m < 16; m <<= 1) ss += __shfl_xor(ss, m, 64);
        rn[j] = rnorm_f(ss);
      }
#pragma unroll
      for (int ct = 0; ct < 4; ++ct)
#pragma unroll
        for (int j = 0; j < 4; ++j) p.h[ct * 4 + j] = f2bs(acc2[ct][j] * rn[j]);
    }
    uint4* d = (uint4*)(outbuf + (size_t)tile * 1024 + l * 16);
    d[0] = p.u[0];
    d[1] = p.u[1];
  }
}

// K3: FOUR triplets per wave — gathers batched up front for ILP.
#define K3_WAVES 20000  // TT/4
__global__ __launch_bounds__(256) void k_triplet(
    const bf16* __restrict__ ckjn, const float* __restrict__ shbs,
    const float* __restrict__ robs, const float* __restrict__ sigxk,
    const int* __restrict__ tri_idx_k, const int* __restrict__ edge_idx_kj,
    const int* __restrict__ edge_idx_ji, float* __restrict__ agg) {
  const int wid = (blockIdx.x * 256 + threadIdx.x) >> 6;
  const int l = threadIdx.x & 63;
  if (wid >= K3_WAVES) return;
  const int lq = l >> 4;
  const int t0 = wid * 4;

  int kj[4], kn[4], ji[4];
#pragma unroll
  for (int i = 0; i < 4; ++i) {
    kj[i] = edge_idx_kj[t0 + i];
    kn[i] = tri_idx_k[t0 + i];
    ji[i] = edge_idx_ji[t0 + i];
  }
  float4 sh[4], rb[4];
  uint4 u0[4], u1[4];
  float sx[4];
#pragma unroll
  for (int i = 0; i < 4; ++i) {
    sh[i] = *(const float4*)(shbs + (size_t)(t0 + i) * DD + lq * 4);
    rb[i] = *(const float4*)(robs + (size_t)kj[i] * DD + lq * 4);
    const uint4* b = (const uint4*)(ckjn + (size_t)kj[i] * 1024 + l * 16);
    u0[i] = b[0];
    u1[i] = b[1];
    sx[i] = sigxk[(size_t)kn[i] * CC + l];
  }

  float acc[4][4];
#pragma unroll
  for (int i = 0; i < 4; ++i) {
    const float w0 = sh[i].x * rb[i].x, w1 = sh[i].y * rb[i].y,
                w2 = sh[i].z * rb[i].z, w3 = sh[i].w * rb[i].w;
    float x0, x1, x2, x3;
    bf2x(u0[i].x, x0, x1); bf2x(u0[i].y, x2, x3);
    acc[i][0] = fmaf(w3, x3, fmaf(w2, x2, fmaf(w1, x1, w0 * x0)));
    bf2x(u0[i].z, x0, x1); bf2x(u0[i].w, x2, x3);
    acc[i][1] = fmaf(w3, x3, fmaf(w2, x2, fmaf(w1, x1, w0 * x0)));
    bf2x(u1[i].x, x0, x1); bf2x(u1[i].y, x2, x3);
    acc[i][2] = fmaf(w3, x3, fmaf(w2, x2, fmaf(w1, x1, w0 * x0)));
    bf2x(u1[i].z, x0, x1); bf2x(u1[i].w, x2, x3);
    acc[i][3] = fmaf(w3, x3, fmaf(w2, x2, fmaf(w1, x1, w0 * x0)));
  }
#pragma unroll
  for (int m = 16; m < 64; m <<= 1)
#pragma unroll
    for (int i = 0; i < 4; ++i)
#pragma unroll
      for (int q = 0; q < 4; ++q) acc[i][q] += __shfl_xor(acc[i][q], m, 64);

  float sel[4], ss[4];
#pragma unroll
  for (int i = 0; i < 4; ++i) {
    sel[i] = (lq == 0) ? acc[i][0] : (lq == 1) ? acc[i][1]
             : (lq == 2) ? acc[i][2] : acc[i][3];
    ss[i] = sel[i] * sel[i];
  }
#pragma unroll
  for (int m = 1; m < 64; m <<= 1)
#pragma unroll
    for (int i = 0; i < 4; ++i) ss[i] += __shfl_xor(ss[i], m, 64);
#pragma unroll
  for (int i = 0; i < 4; ++i) {
    const float tbw = sel[i] * rnorm_f(ss[i]) * sx[i];
    atomicAdd(&agg[(size_t)ji[i] * CC + l], tbw);
  }
}

// K4a (MFMA, 16 edges/wave, grid-stride): onew and m
#define K4A_TILES 3125  // EE/16
#define K4A_BLOCKS 256
__global__ __launch_bounds__(256, 2) void k_edge_a(
    const float* __restrict__ agg, const float* __restrict__ sxq,
    const int* __restrict__ idx_i, const int* __restrict__ idx_j,
    const float* __restrict__ W_t3, const float* __restrict__ b_t3,
    const float* __restrict__ W_n1, const float* __restrict__ b_n1,
    const float* __restrict__ W_n2, const float* __restrict__ b_n2,
    float* __restrict__ onew_buf, float* __restrict__ m_buf) {
  __shared__ __align__(16) float fbuf[4][16 * 68];
  __shared__ __align__(16) short sbuf[4][16 * 72];
  const int tid = threadIdx.x;
  const int w = tid >> 6, l = tid & 63;
  const int lr = l & 15, lg = l >> 4;
  float* fb = fbuf[w];
  short* sb = sbuf[w];

  bf16x8 bt3[2][4], bn1[4][4], bn2[2][4];
#pragma unroll
  for (int kt = 0; kt < 2; ++kt)
#pragma unroll
    for (int nt = 0; nt < 4; ++nt) {
      bf16x8 t;
#pragma unroll
      for (int b = 0; b < 8; ++b)
        t[b] = f2bs(W_t3[(kt * 32 + lg * 8 + b) * 64 + nt * 16 + lr]);
      bt3[kt][nt] = t;
    }
#pragma unroll
  for (int kt = 0; kt < 4; ++kt)
#pragma unroll
    for (int nt = 0; nt < 4; ++nt) {
      bf16x8 t;
#pragma unroll
      for (int b = 0; b < 8; ++b)
        t[b] = f2bs(W_n1[(kt * 32 + lg * 8 + b) * 64 + nt * 16 + lr]);
      bn1[kt][nt] = t;
    }
#pragma unroll
  for (int kt = 0; kt < 2; ++kt)
#pragma unroll
    for (int nt = 0; nt < 4; ++nt) {
      bf16x8 t;
#pragma unroll
      for (int b = 0; b < 8; ++b)
        t[b] = f2bs(W_n2[(kt * 32 + lg * 8 + b) * 64 + nt * 16 + lr]);
      bn2[kt][nt] = t;
    }
  float bt3c[4], bn1c[4], bn2c[4];
#pragma unroll
  for (int nt = 0; nt < 4; ++nt) {
    bt3c[nt] = b_t3[nt * 16 + lr];
    bn1c[nt] = b_n1[nt * 16 + lr];
    bn2c[nt] = b_n2[nt * 16 + lr];
  }

  for (int tile = blockIdx.x * 4 + w; tile < K4A_TILES; tile += K4A_BLOCKS * 4) {
    const int e = tile * 16 + lr;
    const int vi = idx_i[e], vj = idx_j[e];

    bf16x8 aagg[2];
#pragma unroll
    for (int kt = 0; kt < 2; ++kt) {
      const float4 u = *(const float4*)(agg + (size_t)e * 64 + kt * 32 + lg * 8);
      const float4 v = *(const float4*)(agg + (size_t)e * 64 + kt * 32 + lg * 8 + 4);
      bf16x8 t;
      t[0] = f2bs(silu_f(u.x)); t[1] = f2bs(silu_f(u.y));
      t[2] = f2bs(silu_f(u.z)); t[3] = f2bs(silu_f(u.w));
      t[4] = f2bs(silu_f(v.x)); t[5] = f2bs(silu_f(v.y));
      t[6] = f2bs(silu_f(v.z)); t[7] = f2bs(silu_f(v.w));
      aagg[kt] = t;
    }
    f32x4 acc[4];
#pragma unroll
    for (int nt = 0; nt < 4; ++nt) acc[nt] = (f32x4){0.f, 0.f, 0.f, 0.f};
#pragma unroll
    for (int nt = 0; nt < 4; ++nt) {
      acc[nt] = __builtin_amdgcn_mfma_f32_16x16x32_bf16(aagg[0], bt3[0][nt], acc[nt], 0, 0, 0);
      acc[nt] = __builtin_amdgcn_mfma_f32_16x16x32_bf16(aagg[1], bt3[1][nt], acc[nt], 0, 0, 0);
    }
#pragma unroll
    for (int nt = 0; nt < 4; ++nt)
#pragma unroll
      for (int j = 0; j < 4; ++j)
        fb[(lg * 4 + j) * 68 + nt * 16 + lr] = 1.f + bt3c[nt] + acc[nt][j];
    {
      const int row = l >> 2, cs = (l & 3) * 16;
      float* dst = onew_buf + (size_t)(tile * 16 + row) * 64 + cs;
#pragma unroll
      for (int q = 0; q < 4; ++q)
        *(float4*)(dst + q * 4) = *(const float4*)(fb + row * 68 + cs + q * 4);
    }

    bf16x8 am[4];
#pragma unroll
    for (int kt = 0; kt < 4; ++kt) {
      const float* src = (kt < 2) ? (sxq + (size_t)vi * 64 + kt * 32)
                                  : (sxq + (size_t)vj * 64 + (kt - 2) * 32);
      const float4 u = *(const float4*)(src + lg * 8);
      const float4 v = *(const float4*)(src + lg * 8 + 4);
      bf16x8 t;
      t[0] = f2bs(u.x); t[1] = f2bs(u.y); t[2] = f2bs(u.z); t[3] = f2bs(u.w);
      t[4] = f2bs(v.x); t[5] = f2bs(v.y); t[6] = f2bs(v.z); t[7] = f2bs(v.w);
      am[kt] = t;
    }
    f32x4 acc1[4];
#pragma unroll
    for (int nt = 0; nt < 4; ++nt) acc1[nt] = (f32x4){0.f, 0.f, 0.f, 0.f};
#pragma unroll
    for (int nt = 0; nt < 4; ++nt)
#pragma unroll
      for (int kt = 0; kt < 4; ++kt)
        acc1[nt] = __builtin_amdgcn_mfma_f32_16x16x32_bf16(am[kt], bn1[kt][nt], acc1[nt], 0, 0, 0);

#pragma unroll
    for (int nt = 0; nt < 4; ++nt)
#pragma unroll
      for (int j = 0; j < 4; ++j)
        sb[(lg * 4 + j) * 72 + nt * 16 + lr] = f2bs(silu_f(acc1[nt][j] + bn1c[nt]));
    const bf16x8 a20 = *(const bf16x8*)(sb + lr * 72 + lg * 8);
    const bf16x8 a21 = *(const bf16x8*)(sb + lr * 72 + 32 + lg * 8);

    f32x4 acc2[4];
#pragma unroll
    for (int nt = 0; nt < 4; ++nt) acc2[nt] = (f32x4){0.f, 0.f, 0.f, 0.f};
#pragma unroll
    for (int nt = 0; nt < 4; ++nt) {
      acc2[nt] = __builtin_amdgcn_mfma_f32_16x16x32_bf16(a20, bn2[0][nt], acc2[nt], 0, 0, 0);
      acc2[nt] = __builtin_amdgcn_mfma_f32_16x16x32_bf16(a21, bn2[1][nt], acc2[nt], 0, 0, 0);
    }
#pragma unroll
    for (int nt = 0; nt < 4; ++nt)
#pragma unroll
      for (int j = 0; j < 4; ++j)
        fb[(lg * 4 + j) * 68 + nt * 16 + lr] = acc2[nt][j] + bn2c[nt];
    {
      const int row = l >> 2, cs = (l & 3) * 16;
      float* dst = m_buf + (size_t)(tile * 16 + row) * 64 + cs;
#pragma unroll
      for (int q = 0; q < 4; ++q)
        *(float4*)(dst + q * 4) = *(const float4*)(fb + row * 68 + cs + q * 4);
    }
  }
}

// K4b: TWO edges per wave — loads batched for ILP; lane owns a 4x4 patch.
#define K4B_WAVES 25000  // EE/2
__global__ __launch_bounds__(256) void k_edge_b(
    const bf16* __restrict__ cji2, const float* __restrict__ robs,
    const float* __restrict__ onew_buf, const float* __restrict__ m_buf,
    const int* __restrict__ idx_i, float* __restrict__ lacc) {
  const int wid = (blockIdx.x * 256 + threadIdx.x) >> 6;
  const int l = threadIdx.x & 63;
  if (wid >= K4B_WAVES) return;
  const int lq = l >> 4, lr = l & 15;
  const int e0 = wid * 2;

  uint4 u0[2], u1[2];
  float4 rb[2];
  float ow[2][4], mm[2];
  int vi[2];
#pragma unroll
  for (int i = 0; i < 2; ++i) {
    const uint4* base = (const uint4*)(cji2 + (size_t)(e0 + i) * 1024 + l * 16);
    u0[i] = base[0];
    u1[i] = base[1];
    const float* ob = onew_buf + (size_t)(e0 + i) * 64 + lr;
    ow[i][0] = ob[0]; ow[i][1] = ob[16]; ow[i][2] = ob[32]; ow[i][3] = ob[48];
    rb[i] = *(const float4*)(robs + (size_t)(e0 + i) * DD + lq * 4);
    mm[i] = m_buf[(size_t)(e0 + i) * 64 + l];
    vi[i] = idx_i[e0 + i];
  }

  float v[2][16];
#pragma unroll
  for (int i = 0; i < 2; ++i) {
    bf2x(u0[i].x, v[i][0], v[i][1]);   bf2x(u0[i].y, v[i][2], v[i][3]);
    bf2x(u0[i].z, v[i][4], v[i][5]);   bf2x(u0[i].w, v[i][6], v[i][7]);
    bf2x(u1[i].x, v[i][8], v[i][9]);   bf2x(u1[i].y, v[i][10], v[i][11]);
    bf2x(u1[i].z, v[i][12], v[i][13]); bf2x(u1[i].w, v[i][14], v[i][15]);
#pragma unroll
    for (int j = 0; j < 4; ++j) {
      v[i][j] *= ow[i][0];
      v[i][4 + j] *= ow[i][1];
      v[i][8 + j] *= ow[i][2];
      v[i][12 + j] *= ow[i][3];
    }
  }
  float sq[2][4];
#pragma unroll
  for (int i = 0; i < 2; ++i)
#pragma unroll
    for (int j = 0; j < 4; ++j)
      sq[i][j] = fmaf(v[i][j], v[i][j],
                 fmaf(v[i][4 + j], v[i][4 + j],
                 fmaf(v[i][8 + j], v[i][8 + j], v[i][12 + j] * v[i][12 + j])));
#pragma unroll
  for (int m = 1; m < 16; m <<= 1)
#pragma unroll
    for (int i = 0; i < 2; ++i)
#pragma unroll
      for (int j = 0; j < 4; ++j) sq[i][j] += __shfl_xor(sq[i][j], m, 64);

  float lcq[2][4];
#pragma unroll
  for (int i = 0; i < 2; ++i) {
    const float t0 = rb[i].x * rnorm_f(sq[i][0]),
                t1 = rb[i].y * rnorm_f(sq[i][1]),
                t2 = rb[i].z * rnorm_f(sq[i][2]),
                t3 = rb[i].w * rnorm_f(sq[i][3]);
#pragma unroll
    for (int q = 0; q < 4; ++q)
      lcq[i][q] = fmaf(t0, v[i][q * 4 + 0],
                  fmaf(t1, v[i][q * 4 + 1],
                  fmaf(t2, v[i][q * 4 + 2], t3 * v[i][q * 4 + 3])));
  }
#pragma unroll
  for (int m = 16; m < 64; m <<= 1)
#pragma unroll
    for (int i = 0; i < 2; ++i)
#pragma unroll
      for (int q = 0; q < 4; ++q) lcq[i][q] += __shfl_xor(lcq[i][q], m, 64);

  float sel[2], ss[2];
#pragma unroll
  for (int i = 0; i < 2; ++i) {
    sel[i] = (lq == 0) ? lcq[i][0] : (lq == 1) ? lcq[i][1]
             : (lq == 2) ? lcq[i][2] : lcq[i][3];
    ss[i] = sel[i] * sel[i];
  }
#pragma unroll
  for (int m = 1; m < 64; m <<= 1)
#pragma unroll
    for (int i = 0; i < 2; ++i) ss[i] += __shfl_xor(ss[i], m, 64);
#pragma unroll
  for (int i = 0; i < 2; ++i) {
    const float lcao = sel[i] * rnorm_f(ss[i]);
    atomicAdd(&lacc[(size_t)vi[i] * CC + l], lcao * mm[i]);
  }
}

// K5: 8 nodes/block — W_na streamed once per block.
__global__ __launch_bounds__(128) void k_out(
    const float* __restrict__ x, const float* __restrict__ lacc,
    const float* __restrict__ W_na, float* __restrict__ out) {
  __shared__ __align__(16) float ls[8][CC];
  const int t = threadIdx.x;
  const int base = blockIdx.x * 8;
  for (int idx = t; idx < 8 * CC; idx += 128)
    ls[idx >> 6][idx & 63] = lacc[(size_t)(base + (idx >> 6)) * CC + (idx & 63)];
  __syncthreads();
  float acc[8];
#pragma unroll
  for (int i = 0; i < 8; ++i) acc[i] = x[(size_t)(base + i) * HH + t];
  for (int k = 0; k < CC; k += 4) {
    const float w0 = W_na[(k + 0) * HH + t];
    const float w1 = W_na[(k + 1) * HH + t];
    const float w2 = W_na[(k + 2) * HH + t];
    const float w3 = W_na[(k + 3) * HH + t];
#pragma unroll
    for (int i = 0; i < 8; ++i) {
      const float4 lv = *(const float4*)(&ls[i][k]);
      acc[i] = fmaf(lv.x, w0, acc[i]);
      acc[i] = fmaf(lv.y, w1, acc[i]);
      acc[i] = fmaf(lv.z, w2, acc[i]);
      acc[i] = fmaf(lv.w, w3, acc[i]);
    }
  }
#pragma unroll
  for (int i = 0; i < 8; ++i) out[(size_t)(base + i) * HH + t] = acc[i];
}

extern "C" void kernel_launch(void* const* d_in, const int* in_sizes, int n_in,
                              void* d_out, int out_size, void* d_ws,
                              size_t ws_size, hipStream_t stream) {
  const float* x = (const float*)d_in[0];
  const float* cji = (const float*)d_in[1];
  const float* robs = (const float*)d_in[2];
  const float* shbs = (const float*)d_in[3];
  const int* idx_i = (const int*)d_in[4];
  const int* idx_j = (const int*)d_in[5];
  const int* tri_idx_k = (const int*)d_in[6];
  const int* edge_idx_kj = (const int*)d_in[7];
  const int* edge_idx_ji = (const int*)d_in[8];
  const float* W_nb = (const float*)d_in[9];
  const float* b_nb = (const float*)d_in[10];
  const float* W_c1 = (const float*)d_in[11];
  const float* W_c2 = (const float*)d_in[12];
  const float* W_t3 = (const float*)d_in[13];
  const float* b_t3 = (const float*)d_in[14];
  const float* W_n1 = (const float*)d_in[15];
  const float* b_n1 = (const float*)d_in[16];
  const float* W_n2 = (const float*)d_in[17];
  const float* b_n2 = (const float*)d_in[18];
  const float* W_na = (const float*)d_in[19];
  float* out = (float*)d_out;

  char* ws = (char*)d_ws;
  const size_t NC4 = (size_t)NN * CC * 4;          // 2,560,000
  const size_t EDC2 = (size_t)EE * DD * CC * 2;    // 102,400,000
  const size_t EC4 = (size_t)EE * CC * 4;          // 12,800,000
  float* sxq = (float*)(ws);
  float* sigxk = (float*)(ws + NC4);
  bf16* cji2 = (bf16*)(ws + 2 * NC4);
  bf16* ckjn = (bf16*)(ws + 2 * NC4 + EDC2);
  float* agg = (float*)(ws + 2 * NC4 + 2 * EDC2);
  float* lacc = (float*)(ws + 2 * NC4 + 2 * EDC2 + EC4);
  float* onew_buf = (float*)(ws + 2 * NC4 + EDC2);
  float* m_buf = (float*)(ws + 2 * NC4 + EDC2 + EC4);

  k_coeffs_h<0><<<K2_BLOCKS, 256, 0, stream>>>(cji, W_c1, W_c2, cji2, x,
                                               W_nb, b_nb, sxq, sigxk,
                                               (uint4*)agg);
  k_coeffs_h<1><<<K2_BLOCKS, 256, 0, stream>>>(cji, W_c1, W_c2, ckjn, x,
                                               W_nb, b_nb, sxq, sigxk,
                                               (uint4*)agg);
  k_triplet<<<(K3_WAVES + 3) / 4, 256, 0, stream>>>(ckjn, shbs, robs, sigxk,
                                                    tri_idx_k, edge_idx_kj,
                                                    edge_idx_ji, agg);
  k_edge_a<<<K4A_BLOCKS, 256, 0, stream>>>(
      agg, sxq, idx_i, idx_j, W_t3, b_t3, W_n1, b_n1, W_n2, b_n2, onew_buf,
      m_buf);
  k_edge_b<<<(K4B_WAVES + 3) / 4, 256, 0, stream>>>(cji2, robs, onew_buf,
                                                    m_buf, idx_i, lacc);
  k_out<<<NN / 8, 128, 0, stream>>>(x, lacc, W_na, out);
}

// Round 20
// 193.524 us; speedup vs baseline: 1.2284x; 1.2284x over previous
//
#include <hip/hip_runtime.h>
#include <hip/hip_bf16.h>

#define NN 10000
#define EE 50000
#define TT 80000
#define DD 16
#define HH 128
#define CC 64

typedef __hip_bfloat16 bf16;
typedef __attribute__((ext_vector_type(8))) short bf16x8;
typedef __attribute__((ext_vector_type(4))) short bf16x4;
typedef __attribute__((ext_vector_type(4))) float f32x4;

__device__ __forceinline__ float silu_f(float x) {
  return x * __builtin_amdgcn_rcpf(1.f + __expf(-x));
}
__device__ __forceinline__ float sigm_f(float x) {
  return __builtin_amdgcn_rcpf(1.f + __expf(-x));
}

__device__ __forceinline__ short f2bs(float x) {
  __hip_bfloat16 h = __float2bfloat16(x);
  short s;
  __builtin_memcpy(&s, &h, 2);
  return s;
}

__device__ __forceinline__ float rnorm_f(float ss) {
  return __builtin_amdgcn_rcpf(fmaxf(__builtin_amdgcn_sqrtf(ss), 1e-12f));
}

__device__ __forceinline__ void bf2x(unsigned u, float& lo, float& hi) {
  lo = __uint_as_float(u << 16);
  hi = __uint_as_float(u & 0xffff0000u);
}

#define ZERO_U4 960000  // (EE*CC*4 + NN*CC*4) / 16 bytes

// K2 (fused): [zero agg+lacc] + [node projection, first 625 blocks] +
// [swapped-GEMM coeffs MLP, all blocks].
#define K2_BLOCKS 2048
#define K2_TILES 50000  // (EE*DD)/16
__global__ __launch_bounds__(256, 2) void k_coeffs(
    const float* __restrict__ cji, const float* __restrict__ W_c1,
    const float* __restrict__ W_c2, bf16* __restrict__ cji2,
    bf16* __restrict__ ckjn, const float* __restrict__ x,
    const float* __restrict__ W_nb, const float* __restrict__ b_nb,
    float* __restrict__ sxq, float* __restrict__ sigxk,
    uint4* __restrict__ zero_p) {
  __shared__ __align__(16) float xs[16][HH];
  const int tid = threadIdx.x;
  const int bid = blockIdx.x;
  const int w = tid >> 6, l = tid & 63;
  const int lr = l & 15, lg = l >> 4;

  for (int i = bid * 256 + tid; i < ZERO_U4; i += K2_BLOCKS * 256)
    zero_p[i] = (uint4){0u, 0u, 0u, 0u};

  if (bid < NN / 16) {
    const int g = tid >> 7, c = tid & 127;
    const int nb = bid * 16 + g * 8;
#pragma unroll
    for (int i = 0; i < 8; ++i)
      xs[g * 8 + i][c] = x[(size_t)(nb + i) * HH + c];
    __syncthreads();
    float acc[8];
    const float bb = b_nb[c];
#pragma unroll
    for (int i = 0; i < 8; ++i) acc[i] = bb;
    for (int k = 0; k < HH; k += 4) {
      const float w0 = W_nb[(k + 0) * HH + c];
      const float w1 = W_nb[(k + 1) * HH + c];
      const float w2 = W_nb[(k + 2) * HH + c];
      const float w3 = W_nb[(k + 3) * HH + c];
#pragma unroll
      for (int i = 0; i < 8; ++i) {
        const float4 xv = *(const float4*)(&xs[g * 8 + i][k]);
        acc[i] = fmaf(xv.x, w0, acc[i]);
        acc[i] = fmaf(xv.y, w1, acc[i]);
        acc[i] = fmaf(xv.z, w2, acc[i]);
        acc[i] = fmaf(xv.w, w3, acc[i]);
      }
    }
    if (c < CC) {
#pragma unroll
      for (int i = 0; i < 8; ++i)
        sxq[(size_t)(nb + i) * CC + c] = silu_f(acc[i]);
    } else {
#pragma unroll
      for (int i = 0; i < 8; ++i)
        sigxk[(size_t)(nb + i) * CC + (c - CC)] = sigm_f(acc[i]);
    }
  }

  bf16x4 bw1[4][4];
  bf16x4 bw2[4][8];
#pragma unroll
  for (int rt = 0; rt < 4; ++rt)
#pragma unroll
    for (int kt = 0; kt < 4; ++kt) {
      bf16x4 t;
#pragma unroll
      for (int b = 0; b < 4; ++b)
        t[b] = f2bs(W_c1[(kt * 16 + lg * 4 + b) * 64 + rt * 16 + lr]);
      bw1[rt][kt] = t;
    }
#pragma unroll
  for (int kt = 0; kt < 4; ++kt)
#pragma unroll
    for (int ct = 0; ct < 8; ++ct) {
      bf16x4 t;
#pragma unroll
      for (int b = 0; b < 4; ++b)
        t[b] = f2bs(W_c2[(kt * 16 + lg * 4 + b) * 128 + ct * 16 + lr]);
      bw2[kt][ct] = t;
    }

  const int nwave = K2_BLOCKS * 4;
  int tile = bid * 4 + w;
  if (tile >= K2_TILES) return;

  float4 r[4];
#pragma unroll
  for (int kt = 0; kt < 4; ++kt)
    r[kt] = *(const float4*)(cji + (size_t)tile * 1024 + lr * 64 + kt * 16 + lg * 4);

  for (; tile < K2_TILES; tile += nwave) {
    bf16x4 sB[4];
#pragma unroll
    for (int kt = 0; kt < 4; ++kt) {
      bf16x4 t;
      t[0] = f2bs(silu_f(r[kt].x));
      t[1] = f2bs(silu_f(r[kt].y));
      t[2] = f2bs(silu_f(r[kt].z));
      t[3] = f2bs(silu_f(r[kt].w));
      sB[kt] = t;
    }

    const int next = tile + nwave;
    if (next < K2_TILES) {
#pragma unroll
      for (int kt = 0; kt < 4; ++kt)
        r[kt] = *(const float4*)(cji + (size_t)next * 1024 + lr * 64 + kt * 16 + lg * 4);
    }

    f32x4 acc1[4];
#pragma unroll
    for (int rt = 0; rt < 4; ++rt) acc1[rt] = (f32x4){0.f, 0.f, 0.f, 0.f};
#pragma unroll
    for (int rt = 0; rt < 4; ++rt)
#pragma unroll
      for (int kt = 0; kt < 4; ++kt)
        acc1[rt] = __builtin_amdgcn_mfma_f32_16x16x16bf16_1k(bw1[rt][kt], sB[kt], acc1[rt], 0, 0, 0);

    bf16x4 tf[4];
#pragma unroll
    for (int kt = 0; kt < 4; ++kt) {
      bf16x4 t;
#pragma unroll
      for (int b = 0; b < 4; ++b) t[b] = f2bs(silu_f(acc1[kt][b]));
      tf[kt] = t;
    }

    f32x4 acc2[8];
#pragma unroll
    for (int ct = 0; ct < 8; ++ct) acc2[ct] = (f32x4){0.f, 0.f, 0.f, 0.f};
#pragma unroll
    for (int ct = 0; ct < 8; ++ct)
#pragma unroll
      for (int kt = 0; kt < 4; ++kt)
        acc2[ct] = __builtin_amdgcn_mfma_f32_16x16x16bf16_1k(tf[kt], bw2[kt][ct], acc2[ct], 0, 0, 0);

    float rn[4];
#pragma unroll
    for (int j = 0; j < 4; ++j) {
      float ss = acc2[4][j] * acc2[4][j];
      ss = fmaf(acc2[5][j], acc2[5][j], ss);
      ss = fmaf(acc2[6][j], acc2[6][j], ss);
      ss = fmaf(acc2[7][j], acc2[7][j], ss);
#pragma unroll
      for (int m = 1; m < 16; m <<= 1) ss += __shfl_xor(ss, m, 64);
      rn[j] = rnorm_f(ss);
    }

    union { short h[16]; uint4 u[2]; } p;
#pragma unroll
    for (int ct = 0; ct < 4; ++ct)
#pragma unroll
      for (int j = 0; j < 4; ++j) p.h[ct * 4 + j] = f2bs(acc2[ct][j]);
    {
      uint4* d0 = (uint4*)(cji2 + (size_t)tile * 1024 + l * 16);
      d0[0] = p.u[0];
      d0[1] = p.u[1];
    }
#pragma unroll
    for (int ct = 0; ct < 4; ++ct)
#pragma unroll
      for (int j = 0; j < 4; ++j) p.h[ct * 4 + j] = f2bs(acc2[4 + ct][j] * rn[j]);
    {
      uint4* d1 = (uint4*)(ckjn + (size_t)tile * 1024 + l * 16);
      d1[0] = p.u[0];
      d1[1] = p.u[1];
    }
  }
}

// K3: FOUR triplets per wave — gathers batched up front for ILP.
#define K3_WAVES 20000  // TT/4
__global__ __launch_bounds__(256) void k_triplet(
    const bf16* __restrict__ ckjn, const float* __restrict__ shbs,
    const float* __restrict__ robs, const float* __restrict__ sigxk,
    const int* __restrict__ tri_idx_k, const int* __restrict__ edge_idx_kj,
    const int* __restrict__ edge_idx_ji, float* __restrict__ agg) {
  const int wid = (blockIdx.x * 256 + threadIdx.x) >> 6;
  const int l = threadIdx.x & 63;
  if (wid >= K3_WAVES) return;
  const int lq = l >> 4;
  const int t0 = wid * 4;

  int kj[4], kn[4], ji[4];
#pragma unroll
  for (int i = 0; i < 4; ++i) {
    kj[i] = edge_idx_kj[t0 + i];
    kn[i] = tri_idx_k[t0 + i];
    ji[i] = edge_idx_ji[t0 + i];
  }
  float4 sh[4], rb[4];
  uint4 u0[4], u1[4];
  float sx[4];
#pragma unroll
  for (int i = 0; i < 4; ++i) {
    sh[i] = *(const float4*)(shbs + (size_t)(t0 + i) * DD + lq * 4);
    rb[i] = *(const float4*)(robs + (size_t)kj[i] * DD + lq * 4);
    const uint4* b = (const uint4*)(ckjn + (size_t)kj[i] * 1024 + l * 16);
    u0[i] = b[0];
    u1[i] = b[1];
    sx[i] = sigxk[(size_t)kn[i] * CC + l];
  }

  float acc[4][4];
#pragma unroll
  for (int i = 0; i < 4; ++i) {
    const float w0 = sh[i].x * rb[i].x, w1 = sh[i].y * rb[i].y,
                w2 = sh[i].z * rb[i].z, w3 = sh[i].w * rb[i].w;
    float x0, x1, x2, x3;
    bf2x(u0[i].x, x0, x1); bf2x(u0[i].y, x2, x3);
    acc[i][0] = fmaf(w3, x3, fmaf(w2, x2, fmaf(w1, x1, w0 * x0)));
    bf2x(u0[i].z, x0, x1); bf2x(u0[i].w, x2, x3);
    acc[i][1] = fmaf(w3, x3, fmaf(w2, x2, fmaf(w1, x1, w0 * x0)));
    bf2x(u1[i].x, x0, x1); bf2x(u1[i].y, x2, x3);
    acc[i][2] = fmaf(w3, x3, fmaf(w2, x2, fmaf(w1, x1, w0 * x0)));
    bf2x(u1[i].z, x0, x1); bf2x(u1[i].w, x2, x3);
    acc[i][3] = fmaf(w3, x3, fmaf(w2, x2, fmaf(w1, x1, w0 * x0)));
  }
#pragma unroll
  for (int m = 16; m < 64; m <<= 1)
#pragma unroll
    for (int i = 0; i < 4; ++i)
#pragma unroll
      for (int q = 0; q < 4; ++q) acc[i][q] += __shfl_xor(acc[i][q], m, 64);

  float sel[4], ss[4];
#pragma unroll
  for (int i = 0; i < 4; ++i) {
    sel[i] = (lq == 0) ? acc[i][0] : (lq == 1) ? acc[i][1]
             : (lq == 2) ? acc[i][2] : acc[i][3];
    ss[i] = sel[i] * sel[i];
  }
#pragma unroll
  for (int m = 1; m < 64; m <<= 1)
#pragma unroll
    for (int i = 0; i < 4; ++i) ss[i] += __shfl_xor(ss[i], m, 64);
#pragma unroll
  for (int i = 0; i < 4; ++i) {
    const float tbw = sel[i] * rnorm_f(ss[i]) * sx[i];
    atomicAdd(&agg[(size_t)ji[i] * CC + l], tbw);
  }
}

// K4a (MFMA, 16 edges/wave, grid-stride): onew and m
#define K4A_TILES 3125  // EE/16
#define K4A_BLOCKS 256
__global__ __launch_bounds__(256, 2) void k_edge_a(
    const float* __restrict__ agg, const float* __restrict__ sxq,
    const int* __restrict__ idx_i, const int* __restrict__ idx_j,
    const float* __restrict__ W_t3, const float* __restrict__ b_t3,
    const float* __restrict__ W_n1, const float* __restrict__ b_n1,
    const float* __restrict__ W_n2, const float* __restrict__ b_n2,
    float* __restrict__ onew_buf, float* __restrict__ m_buf) {
  __shared__ __align__(16) float fbuf[4][16 * 68];
  __shared__ __align__(16) short sbuf[4][16 * 72];
  const int tid = threadIdx.x;
  const int w = tid >> 6, l = tid & 63;
  const int lr = l & 15, lg = l >> 4;
  float* fb = fbuf[w];
  short* sb = sbuf[w];

  bf16x8 bt3[2][4], bn1[4][4], bn2[2][4];
#pragma unroll
  for (int kt = 0; kt < 2; ++kt)
#pragma unroll
    for (int nt = 0; nt < 4; ++nt) {
      bf16x8 t;
#pragma unroll
      for (int b = 0; b < 8; ++b)
        t[b] = f2bs(W_t3[(kt * 32 + lg * 8 + b) * 64 + nt * 16 + lr]);
      bt3[kt][nt] = t;
    }
#pragma unroll
  for (int kt = 0; kt < 4; ++kt)
#pragma unroll
    for (int nt = 0; nt < 4; ++nt) {
      bf16x8 t;
#pragma unroll
      for (int b = 0; b < 8; ++b)
        t[b] = f2bs(W_n1[(kt * 32 + lg * 8 + b) * 64 + nt * 16 + lr]);
      bn1[kt][nt] = t;
    }
#pragma unroll
  for (int kt = 0; kt < 2; ++kt)
#pragma unroll
    for (int nt = 0; nt < 4; ++nt) {
      bf16x8 t;
#pragma unroll
      for (int b = 0; b < 8; ++b)
        t[b] = f2bs(W_n2[(kt * 32 + lg * 8 + b) * 64 + nt * 16 + lr]);
      bn2[kt][nt] = t;
    }
  float bt3c[4], bn1c[4], bn2c[4];
#pragma unroll
  for (int nt = 0; nt < 4; ++nt) {
    bt3c[nt] = b_t3[nt * 16 + lr];
    bn1c[nt] = b_n1[nt * 16 + lr];
    bn2c[nt] = b_n2[nt * 16 + lr];
  }

  for (int tile = blockIdx.x * 4 + w; tile < K4A_TILES; tile += K4A_BLOCKS * 4) {
    const int e = tile * 16 + lr;
    const int vi = idx_i[e], vj = idx_j[e];

    bf16x8 aagg[2];
#pragma unroll
    for (int kt = 0; kt < 2; ++kt) {
      const float4 u = *(const float4*)(agg + (size_t)e * 64 + kt * 32 + lg * 8);
      const float4 v = *(const float4*)(agg + (size_t)e * 64 + kt * 32 + lg * 8 + 4);
      bf16x8 t;
      t[0] = f2bs(silu_f(u.x)); t[1] = f2bs(silu_f(u.y));
      t[2] = f2bs(silu_f(u.z)); t[3] = f2bs(silu_f(u.w));
      t[4] = f2bs(silu_f(v.x)); t[5] = f2bs(silu_f(v.y));
      t[6] = f2bs(silu_f(v.z)); t[7] = f2bs(silu_f(v.w));
      aagg[kt] = t;
    }
    f32x4 acc[4];
#pragma unroll
    for (int nt = 0; nt < 4; ++nt) acc[nt] = (f32x4){0.f, 0.f, 0.f, 0.f};
#pragma unroll
    for (int nt = 0; nt < 4; ++nt) {
      acc[nt] = __builtin_amdgcn_mfma_f32_16x16x32_bf16(aagg[0], bt3[0][nt], acc[nt], 0, 0, 0);
      acc[nt] = __builtin_amdgcn_mfma_f32_16x16x32_bf16(aagg[1], bt3[1][nt], acc[nt], 0, 0, 0);
    }
#pragma unroll
    for (int nt = 0; nt < 4; ++nt)
#pragma unroll
      for (int j = 0; j < 4; ++j)
        fb[(lg * 4 + j) * 68 + nt * 16 + lr] = 1.f + bt3c[nt] + acc[nt][j];
    {
      const int row = l >> 2, cs = (l & 3) * 16;
      float* dst = onew_buf + (size_t)(tile * 16 + row) * 64 + cs;
#pragma unroll
      for (int q = 0; q < 4; ++q)
        *(float4*)(dst + q * 4) = *(const float4*)(fb + row * 68 + cs + q * 4);
    }

    bf16x8 am[4];
#pragma unroll
    for (int kt = 0; kt < 4; ++kt) {
      const float* src = (kt < 2) ? (sxq + (size_t)vi * 64 + kt * 32)
                                  : (sxq + (size_t)vj * 64 + (kt - 2) * 32);
      const float4 u = *(const float4*)(src + lg * 8);
      const float4 v = *(const float4*)(src + lg * 8 + 4);
      bf16x8 t;
      t[0] = f2bs(u.x); t[1] = f2bs(u.y); t[2] = f2bs(u.z); t[3] = f2bs(u.w);
      t[4] = f2bs(v.x); t[5] = f2bs(v.y); t[6] = f2bs(v.z); t[7] = f2bs(v.w);
      am[kt] = t;
    }
    f32x4 acc1[4];
#pragma unroll
    for (int nt = 0; nt < 4; ++nt) acc1[nt] = (f32x4){0.f, 0.f, 0.f, 0.f};
#pragma unroll
    for (int nt = 0; nt < 4; ++nt)
#pragma unroll
      for (int kt = 0; kt < 4; ++kt)
        acc1[nt] = __builtin_amdgcn_mfma_f32_16x16x32_bf16(am[kt], bn1[kt][nt], acc1[nt], 0, 0, 0);

#pragma unroll
    for (int nt = 0; nt < 4; ++nt)
#pragma unroll
      for (int j = 0; j < 4; ++j)
        sb[(lg * 4 + j) * 72 + nt * 16 + lr] = f2bs(silu_f(acc1[nt][j] + bn1c[nt]));
    const bf16x8 a20 = *(const bf16x8*)(sb + lr * 72 + lg * 8);
    const bf16x8 a21 = *(const bf16x8*)(sb + lr * 72 + 32 + lg * 8);

    f32x4 acc2[4];
#pragma unroll
    for (int nt = 0; nt < 4; ++nt) acc2[nt] = (f32x4){0.f, 0.f, 0.f, 0.f};
#pragma unroll
    for (int nt = 0; nt < 4; ++nt) {
      acc2[nt] = __builtin_amdgcn_mfma_f32_16x16x32_bf16(a20, bn2[0][nt], acc2[nt], 0, 0, 0);
      acc2[nt] = __builtin_amdgcn_mfma_f32_16x16x32_bf16(a21, bn2[1][nt], acc2[nt], 0, 0, 0);
    }
#pragma unroll
    for (int nt = 0; nt < 4; ++nt)
#pragma unroll
      for (int j = 0; j < 4; ++j)
        fb[(lg * 4 + j) * 68 + nt * 16 + lr] = acc2[nt][j] + bn2c[nt];
    {
      const int row = l >> 2, cs = (l & 3) * 16;
      float* dst = m_buf + (size_t)(tile * 16 + row) * 64 + cs;
#pragma unroll
      for (int q = 0; q < 4; ++q)
        *(float4*)(dst + q * 4) = *(const float4*)(fb + row * 68 + cs + q * 4);
    }
  }
}

// K4b: TWO edges per wave — loads batched for ILP; lane owns a 4x4 patch.
#define K4B_WAVES 25000  // EE/2
__global__ __launch_bounds__(256) void k_edge_b(
    const bf16* __restrict__ cji2, const float* __restrict__ robs,
    const float* __restrict__ onew_buf, const float* __restrict__ m_buf,
    const int* __restrict__ idx_i, float* __restrict__ lacc) {
  const int wid = (blockIdx.x * 256 + threadIdx.x) >> 6;
  const int l = threadIdx.x & 63;
  if (wid >= K4B_WAVES) return;
  const int lq = l >> 4, lr = l & 15;
  const int e0 = wid * 2;

  uint4 u0[2], u1[2];
  float4 rb[2];
  float ow[2][4], mm[2];
  int vi[2];
#pragma unroll
  for (int i = 0; i < 2; ++i) {
    const uint4* base = (const uint4*)(cji2 + (size_t)(e0 + i) * 1024 + l * 16);
    u0[i] = base[0];
    u1[i] = base[1];
    const float* ob = onew_buf + (size_t)(e0 + i) * 64 + lr;
    ow[i][0] = ob[0]; ow[i][1] = ob[16]; ow[i][2] = ob[32]; ow[i][3] = ob[48];
    rb[i] = *(const float4*)(robs + (size_t)(e0 + i) * DD + lq * 4);
    mm[i] = m_buf[(size_t)(e0 + i) * 64 + l];
    vi[i] = idx_i[e0 + i];
  }

  float v[2][16];
#pragma unroll
  for (int i = 0; i < 2; ++i) {
    bf2x(u0[i].x, v[i][0], v[i][1]);   bf2x(u0[i].y, v[i][2], v[i][3]);
    bf2x(u0[i].z, v[i][4], v[i][5]);   bf2x(u0[i].w, v[i][6], v[i][7]);
    bf2x(u1[i].x, v[i][8], v[i][9]);   bf2x(u1[i].y, v[i][10], v[i][11]);
    bf2x(u1[i].z, v[i][12], v[i][13]); bf2x(u1[i].w, v[i][14], v[i][15]);
#pragma unroll
    for (int j = 0; j < 4; ++j) {
      v[i][j] *= ow[i][0];
      v[i][4 + j] *= ow[i][1];
      v[i][8 + j] *= ow[i][2];
      v[i][12 + j] *= ow[i][3];
    }
  }
  float sq[2][4];
#pragma unroll
  for (int i = 0; i < 2; ++i)
#pragma unroll
    for (int j = 0; j < 4; ++j)
      sq[i][j] = fmaf(v[i][j], v[i][j],
                 fmaf(v[i][4 + j], v[i][4 + j],
                 fmaf(v[i][8 + j], v[i][8 + j], v[i][12 + j] * v[i][12 + j])));
#pragma unroll
  for (int m = 1; m < 16; m <<= 1)
#pragma unroll
    for (int i = 0; i < 2; ++i)
#pragma unroll
      for (int j = 0; j < 4; ++j) sq[i][j] += __shfl_xor(sq[i][j], m, 64);

  float lcq[2][4];
#pragma unroll
  for (int i = 0; i < 2; ++i) {
    const float t0 = rb[i].x * rnorm_f(sq[i][0]),
                t1 = rb[i].y * rnorm_f(sq[i][1]),
                t2 = rb[i].z * rnorm_f(sq[i][2]),
                t3 = rb[i].w * rnorm_f(sq[i][3]);
#pragma unroll
    for (int q = 0; q < 4; ++q)
      lcq[i][q] = fmaf(t0, v[i][q * 4 + 0],
                  fmaf(t1, v[i][q * 4 + 1],
                  fmaf(t2, v[i][q * 4 + 2], t3 * v[i][q * 4 + 3])));
  }
#pragma unroll
  for (int m = 16; m < 64; m <<= 1)
#pragma unroll
    for (int i = 0; i < 2; ++i)
#pragma unroll
      for (int q = 0; q < 4; ++q) lcq[i][q] += __shfl_xor(lcq[i][q], m, 64);

  float sel[2], ss[2];
#pragma unroll
  for (int i = 0; i < 2; ++i) {
    sel[i] = (lq == 0) ? lcq[i][0] : (lq == 1) ? lcq[i][1]
             : (lq == 2) ? lcq[i][2] : lcq[i][3];
    ss[i] = sel[i] * sel[i];
  }
#pragma unroll
  for (int m = 1; m < 64; m <<= 1)
#pragma unroll
    for (int i = 0; i < 2; ++i) ss[i] += __shfl_xor(ss[i], m, 64);
#pragma unroll
  for (int i = 0; i < 2; ++i) {
    const float lcao = sel[i] * rnorm_f(ss[i]);
    atomicAdd(&lacc[(size_t)vi[i] * CC + l], lcao * mm[i]);
  }
}

// K5: 8 nodes/block — W_na streamed once per block.
__global__ __launch_bounds__(128) void k_out(
    const float* __restrict__ x, const float* __restrict__ lacc,
    const float* __restrict__ W_na, float* __restrict__ out) {
  __shared__ __align__(16) float ls[8][CC];
  const int t = threadIdx.x;
  const int base = blockIdx.x * 8;
  for (int idx = t; idx < 8 * CC; idx += 128)
    ls[idx >> 6][idx & 63] = lacc[(size_t)(base + (idx >> 6)) * CC + (idx & 63)];
  __syncthreads();
  float acc[8];
#pragma unroll
  for (int i = 0; i < 8; ++i) acc[i] = x[(size_t)(base + i) * HH + t];
  for (int k = 0; k < CC; k += 4) {
    const float w0 = W_na[(k + 0) * HH + t];
    const float w1 = W_na[(k + 1) * HH + t];
    const float w2 = W_na[(k + 2) * HH + t];
    const float w3 = W_na[(k + 3) * HH + t];
#pragma unroll
    for (int i = 0; i < 8; ++i) {
      const float4 lv = *(const float4*)(&ls[i][k]);
      acc[i] = fmaf(lv.x, w0, acc[i]);
      acc[i] = fmaf(lv.y, w1, acc[i]);
      acc[i] = fmaf(lv.z, w2, acc[i]);
      acc[i] = fmaf(lv.w, w3, acc[i]);
    }
  }
#pragma unroll
  for (int i = 0; i < 8; ++i) out[(size_t)(base + i) * HH + t] = acc[i];
}

extern "C" void kernel_launch(void* const* d_in, const int* in_sizes, int n_in,
                              void* d_out, int out_size, void* d_ws,
                              size_t ws_size, hipStream_t stream) {
  const float* x = (const float*)d_in[0];
  const float* cji = (const float*)d_in[1];
  const float* robs = (const float*)d_in[2];
  const float* shbs = (const float*)d_in[3];
  const int* idx_i = (const int*)d_in[4];
  const int* idx_j = (const int*)d_in[5];
  const int* tri_idx_k = (const int*)d_in[6];
  const int* edge_idx_kj = (const int*)d_in[7];
  const int* edge_idx_ji = (const int*)d_in[8];
  const float* W_nb = (const float*)d_in[9];
  const float* b_nb = (const float*)d_in[10];
  const float* W_c1 = (const float*)d_in[11];
  const float* W_c2 = (const float*)d_in[12];
  const float* W_t3 = (const float*)d_in[13];
  const float* b_t3 = (const float*)d_in[14];
  const float* W_n1 = (const float*)d_in[15];
  const float* b_n1 = (const float*)d_in[16];
  const float* W_n2 = (const float*)d_in[17];
  const float* b_n2 = (const float*)d_in[18];
  const float* W_na = (const float*)d_in[19];
  float* out = (float*)d_out;

  char* ws = (char*)d_ws;
  const size_t NC4 = (size_t)NN * CC * 4;          // 2,560,000
  const size_t EDC2 = (size_t)EE * DD * CC * 2;    // 102,400,000
  const size_t EC4 = (size_t)EE * CC * 4;          // 12,800,000
  float* sxq = (float*)(ws);
  float* sigxk = (float*)(ws + NC4);
  bf16* cji2 = (bf16*)(ws + 2 * NC4);
  bf16* ckjn = (bf16*)(ws + 2 * NC4 + EDC2);
  float* agg = (float*)(ws + 2 * NC4 + 2 * EDC2);
  float* lacc = (float*)(ws + 2 * NC4 + 2 * EDC2 + EC4);
  float* onew_buf = (float*)(ws + 2 * NC4 + EDC2);
  float* m_buf = (float*)(ws + 2 * NC4 + EDC2 + EC4);

  k_coeffs<<<K2_BLOCKS, 256, 0, stream>>>(cji, W_c1, W_c2, cji2, ckjn, x,
                                          W_nb, b_nb, sxq, sigxk,
                                          (uint4*)agg);
  k_triplet<<<(K3_WAVES + 3) / 4, 256, 0, stream>>>(ckjn, shbs, robs, sigxk,
                                                    tri_idx_k, edge_idx_kj,
                                                    edge_idx_ji, agg);
  k_edge_a<<<K4A_BLOCKS, 256, 0, stream>>>(
      agg, sxq, idx_i, idx_j, W_t3, b_t3, W_n1, b_n1, W_n2, b_n2, onew_buf,
      m_buf);
  k_edge_b<<<(K4B_WAVES + 3) / 4, 256, 0, stream>>>(cji2, robs, onew_buf,
                                                    m_buf, idx_i, lacc);
  k_out<<<NN / 8, 128, 0, stream>>>(x, lacc, W_na, out);
}